// Round 2
// baseline (349.180 us; speedup 1.0000x reference)
//
#include <hip/hip_runtime.h>
#include <math.h>

#define T_ 8
#define B_ 4
#define C_ 128
#define HW_ 9216        // 96*96
#define IN_HW_ 147456   // 384*384

typedef float nat_f4 __attribute__((ext_vector_type(4)));  // for nontemporal stores

// ---------------------------------------------------------------------------
// Bilinear antialias resize 384 -> 96: separable 8-tap triangle filter.
// (unchanged from verified version -- the >0.5 binarization sits on knife-edge
// pixels and must match the f64 reference exactly)
// ---------------------------------------------------------------------------
__device__ __forceinline__ double resize_px(const float* __restrict__ img, int y, int x) {
  static const double wm[8]  = {0.03125, 0.09375, 0.15625, 0.21875,
                                0.21875, 0.15625, 0.09375, 0.03125};
  static const double w0[8]  = {0.0, 0.0, 0.625/3.5, 0.875/3.5,
                                0.875/3.5, 0.625/3.5, 0.375/3.5, 0.125/3.5};
  static const double w95[8] = {0.125/3.5, 0.375/3.5, 0.625/3.5, 0.875/3.5,
                                0.875/3.5, 0.625/3.5, 0.0, 0.0};
  const double* wy = (y == 0) ? w0 : (y == 95 ? w95 : wm);
  const double* wx = (x == 0) ? w0 : (x == 95 ? w95 : wm);
  double acc = 0.0;
#pragma unroll
  for (int ky = 0; ky < 8; ++ky) {
    double wyv = wy[ky];
    if (wyv == 0.0) continue;
    int jy = 4 * y - 2 + ky;
    const float* row = img + jy * 384;
    double ra = 0.0;
#pragma unroll
    for (int kx = 0; kx < 8; ++kx) {
      double wxv = wx[kx];
      if (wxv == 0.0) continue;
      int jx = 4 * x - 2 + kx;
      ra += wxv * (double)row[jx];
    }
    acc += wyv * ra;
  }
  return acc;
}

// shuffle-based block sum (256 threads = 4 waves). Result valid on all threads.
// Sums of 0/1 floats are exact regardless of order.
__device__ __forceinline__ float block_sum_256(float v) {
  v += __shfl_xor(v, 1);
  v += __shfl_xor(v, 2);
  v += __shfl_xor(v, 4);
  v += __shfl_xor(v, 8);
  v += __shfl_xor(v, 16);
  v += __shfl_xor(v, 32);
  __shared__ float s[4];
  int lane = threadIdx.x & 63, wv = threadIdx.x >> 6;
  if (lane == 0) s[wv] = v;
  __syncthreads();
  return s[0] + s[1] + s[2] + s[3];
}

__global__ void k_init(float* __restrict__ v_sum) {
  if (threadIdx.x < T_ * B_) v_sum[threadIdx.x] = 0.f;
}

// Fused tv+rv: recompute the tv binarization per (t,b) pixel (deterministic,
// identical result; resize compute is ~1us total). Writes rv, vm, v_sum.
// grid: (HW/256, T*B), 1 px/thread.
__global__ __launch_bounds__(256) void k_rv(const float* __restrict__ rvmaps,
                                            const float* __restrict__ tvmap,
                                            float* __restrict__ rv, float* __restrict__ vm,
                                            float* __restrict__ v_sum) {
  int tb = blockIdx.y;          // t*B + b
  int b = tb % B_;
  int p = blockIdx.x * 256 + threadIdx.x;
  int y = p / 96, x = p % 96;
  float rvv = (resize_px(rvmaps + (size_t)tb * IN_HW_, y, x) > 0.5) ? 1.0f : 0.0f;
  float tvv = (resize_px(tvmap  + (size_t)b  * IN_HW_, y, x) > 0.5) ? 1.0f : 0.0f;
  float vmv = rvv * tvv;
  rv[(size_t)tb * HW_ + p] = rvv;
  vm[(size_t)tb * HW_ + p] = vmv;
  float s = block_sum_256(vmv);
  if (threadIdx.x == 0) atomicAdd(&v_sum[tb], s);
}

// t-major gs pass: block = (ptile, c, b) loads t_feat tile ONCE, streams all
// 8 (vm, r_feats) tiles. t_feat HBM traffic: 18.9 MB (was 151 MB of cache
// re-reads). Deterministic two-stage reduction via gs_part[(t,b,c,ptile)].
// grid: (9, C_, B_), 256 threads, 1 float4 per tensor per thread.
__global__ __launch_bounds__(256) void k_gs(const float* __restrict__ values,
                                            const float* __restrict__ vm,
                                            float* __restrict__ gs_part) {
  int ptile = blockIdx.x;       // 0..8
  int c     = blockIdx.y;       // 0..127
  int b     = blockIdx.z;       // 0..3
  int p0 = ptile * 1024 + threadIdx.x * 4;
  const float4 a = *(const float4*)(values + ((size_t)b * C_ + c) * HW_ + p0);
  float acc[T_];
#pragma unroll
  for (int t = 0; t < T_; ++t) {
    const float4 m = *(const float4*)(vm + ((size_t)(t * B_ + b)) * HW_ + p0);
    const float4 r = *(const float4*)(values + ((size_t)((1 + t) * B_ + b) * C_ + c) * HW_ + p0);
    acc[t] = m.x * a.x * r.x + m.y * a.y * r.y + m.z * a.z * r.z + m.w * a.w * r.w;
  }
  __shared__ float sred[4][T_];
  int lane = threadIdx.x & 63, wv = threadIdx.x >> 6;
#pragma unroll
  for (int t = 0; t < T_; ++t) {
    float v = acc[t];
    v += __shfl_xor(v, 1);
    v += __shfl_xor(v, 2);
    v += __shfl_xor(v, 4);
    v += __shfl_xor(v, 8);
    v += __shfl_xor(v, 16);
    v += __shfl_xor(v, 32);
    if (lane == 0) sred[wv][t] = v;
  }
  __syncthreads();
  if (threadIdx.x < T_) {
    int t = threadIdx.x;
    float s = sred[0][t] + sred[1][t] + sred[2][t] + sred[3][t];
    gs_part[((size_t)(t * B_ + b) * C_ + c) * 9 + ptile] = s;
  }
}

// gs[tb] = where(empty,0,sum)/(v_sum+empty)/C. One block, 256 threads:
// 8 threads per tb, each sums a contiguous 144-float chunk (float4 loads).
__global__ __launch_bounds__(256) void k_gsfin(const float* __restrict__ gs_part,
                                               const float* __restrict__ v_sum,
                                               float* __restrict__ gs,
                                               float* __restrict__ out_gs) {
  __shared__ float sred[32][8];
  int tb = threadIdx.x >> 3, j = threadIdx.x & 7;
  const float4* p = (const float4*)(gs_part + (size_t)tb * (C_ * 9) + j * 144);
  float s = 0.f;
#pragma unroll
  for (int i = 0; i < 36; ++i) {
    float4 v = p[i];
    s += v.x + v.y + v.z + v.w;
  }
  sred[tb][j] = s;
  __syncthreads();
  if (threadIdx.x < 32) {
    int i = threadIdx.x;
    float t = 0.f;
#pragma unroll
    for (int k = 0; k < 8; ++k) t += sred[i][k];
    float vs = v_sum[i];
    bool empty = vs < 1e-4f;
    float g = (empty ? 0.f : t) / (vs + (empty ? 1.f : 0.f)) / (float)C_;
    gs[i] = g;
    out_gs[i] = g;
  }
}

// Softmax-match weights computed ONCE per pixel (was recomputed 16x in the
// old fused epilogue). Writes cm (into dead vm workspace), channel 256 of
// out, and out_cmask. grid: (HW/256, B_), 1 px/thread.
__global__ __launch_bounds__(256) void k_cm(const float* __restrict__ rv,
                                            const float* __restrict__ gs,
                                            float* __restrict__ cm,
                                            float* __restrict__ out,
                                            float* __restrict__ out_cmask) {
  int b = blockIdx.y;
  int p = blockIdx.x * 256 + threadIdx.x;
  __shared__ float gsh[T_];
  if (threadIdx.x < T_) gsh[threadIdx.x] = gs[threadIdx.x * B_ + b];
  __syncthreads();
  float rvv[T_], mv[T_];
  float mx = -1e30f;
#pragma unroll
  for (int t = 0; t < T_; ++t) {
    rvv[t] = rv[((size_t)(t * B_ + b)) * HW_ + p];
    mv[t] = gsh[t] * rvv[t];
    mx = fmaxf(mx, mv[t]);
  }
  float e[T_], ms = 0.f;
#pragma unroll
  for (int t = 0; t < T_; ++t) {
    e[t] = expf(mv[t] - mx) * rvv[t];
    ms += e[t];
  }
  if (ms < 1e-4f) ms += 1.f;
  float inv = 1.f / ms, cs = 0.f;
#pragma unroll
  for (int t = 0; t < T_; ++t) {
    float w = e[t] * inv;
    cm[((size_t)(t * B_ + b)) * HW_ + p] = w;
    cs += w * rvv[t];
  }
  float cmv = 1.f - cs;
  size_t outb = (size_t)b * 257 * HW_;
  out[outb + (size_t)256 * HW_ + p] = cmv;
  out_cmask[(size_t)b * HW_ + p] = cmv;
}

// Lean streaming epilogue: t_feat passthrough + c_out. No softmax state,
// ~90 VGPR, 1152 blocks (was 576 @ 150+ VGPR with 16x softmax recompute).
// grid: (32 ctiles of 4 ch, 9 ptiles, B_), 4 px/thread (float4).
__global__ __launch_bounds__(256) void k_epi(const float* __restrict__ values,
                                             const float* __restrict__ cm,
                                             float* __restrict__ out) {
  int ctile = blockIdx.x;       // 0..31
  int ptile = blockIdx.y;       // 0..8
  int b     = blockIdx.z;       // 0..3
  int p0 = ptile * 1024 + threadIdx.x * 4;

  float4 w[T_];
#pragma unroll
  for (int t = 0; t < T_; ++t)
    w[t] = *(const float4*)(cm + ((size_t)(t * B_ + b)) * HW_ + p0);

  size_t outb = (size_t)b * 257 * HW_;
#pragma unroll 1
  for (int cc = 0; cc < 4; ++cc) {
    int c = ctile * 4 + cc;
    // t_feat passthrough (channels 0..127)
    const float4 tf = *(const float4*)(values + ((size_t)b * C_ + c) * HW_ + p0);
    nat_f4 tfn = {tf.x, tf.y, tf.z, tf.w};
    __builtin_nontemporal_store(tfn, (nat_f4*)(out + outb + (size_t)c * HW_ + p0));
    // c_out (channels 128..255)
    float4 acc = {0.f, 0.f, 0.f, 0.f};
#pragma unroll
    for (int t = 0; t < T_; ++t) {
      const float4 r = *(const float4*)(values +
          ((size_t)((1 + t) * B_ + b) * C_ + c) * HW_ + p0);
      acc.x += w[t].x * r.x;
      acc.y += w[t].y * r.y;
      acc.z += w[t].z * r.z;
      acc.w += w[t].w * r.w;
    }
    nat_f4 accn = {acc.x, acc.y, acc.z, acc.w};
    __builtin_nontemporal_store(accn, (nat_f4*)(out + outb + (size_t)(C_ + c) * HW_ + p0));
  }
}

extern "C" void kernel_launch(void* const* d_in, const int* in_sizes, int n_in,
                              void* d_out, int out_size, void* d_ws, size_t ws_size,
                              hipStream_t stream) {
  const float* values = (const float*)d_in[0];   // (9,4,128,96,96)
  const float* tvmap  = (const float*)d_in[1];   // (4,1,384,384)
  const float* rvmaps = (const float*)d_in[2];   // (8,4,1,384,384)
  float* out = (float*)d_out;

  // workspace layout (floats) -- total ~2.5 MB
  float* ws      = (float*)d_ws;
  float* rv      = ws;                            // T_*B_*HW_ = 294912
  float* vm      = rv + (size_t)T_ * B_ * HW_;    // T_*B_*HW_ = 294912
  float* cmw     = vm;                            // alias: vm dead after k_gs
  float* gs_part = vm + (size_t)T_ * B_ * HW_;    // T_*B_*C_*9 = 36864
  float* v_sum   = gs_part + (size_t)T_ * B_ * C_ * 9;  // 32
  float* gsar    = v_sum + T_ * B_;                     // 32

  // output layout: out(4,257,96,96) | c_mask(4,1,96,96) | gs(8,4)
  float* out_cmask = out + (size_t)B_ * 257 * HW_;
  float* out_gs    = out_cmask + (size_t)B_ * HW_;

  hipLaunchKernelGGL(k_init,  dim3(1),                 dim3(64),  0, stream, v_sum);
  hipLaunchKernelGGL(k_rv,    dim3(HW_ / 256, T_ * B_), dim3(256), 0, stream, rvmaps, tvmap, rv, vm, v_sum);
  hipLaunchKernelGGL(k_gs,    dim3(9, C_, B_),         dim3(256), 0, stream, values, vm, gs_part);
  hipLaunchKernelGGL(k_gsfin, dim3(1),                 dim3(256), 0, stream, gs_part, v_sum, gsar, out_gs);
  hipLaunchKernelGGL(k_cm,    dim3(HW_ / 256, B_),     dim3(256), 0, stream, rv, gsar, cmw, out, out_cmask);
  hipLaunchKernelGGL(k_epi,   dim3(32, 9, B_),         dim3(256), 0, stream, values, cmw, out);
}